// Round 7
// baseline (50.205 us; speedup 1.0000x reference)
//
#include <hip/hip_runtime.h>

// out[b, n*7+c, w] = sum_k x[b, w*3+k-21, c] * kern[n, k]   (n in 0..72)
// out[b, 511,   w] = sum_k x[b, w*3+k-21, 0] * kern[73, k]
// Output (32, 512, 2736) fp32.
//
// R7: perfect balance + long store runs.
//  - tile = 684 w (quarter row), grid (4 wq, 32 b, 2 gp) = 256 blocks = 1/CU.
//  - wave holds 3 windows (chunks lane, lane+64, lane+128) in registers,
//    n-outer loop -> 3 consecutive 1KB stores = 2.7KB contiguous run per row.
//  - gp in grid.z so the two blocks sharing an x-tile map to the same XCD.

typedef float f32x4 __attribute__((ext_vector_type(4)));

constexpr int Bn   = 32;
constexpr int Sn   = 8192;
constexpr int Cn   = 7;
constexpr int Kn   = 8;
constexpr int PADn = 21;
constexpr int Wn   = 2736;
constexpr int OCH  = 512;
constexpr int TW   = 684;            // w per tile (2736/4 exact)
constexpr int CHT  = 171;            // float4 chunks per tile row
constexpr int SAMP = 2057;           // (684-1)*3 + 8
constexpr int CSTR = 2060;           // per-channel LDS stride (mult of 4)

#define LOAD17(dst, src)                                                     \
    *reinterpret_cast<f32x4*>((dst) + 0)  = *reinterpret_cast<const f32x4*>((src) + 0);  \
    *reinterpret_cast<f32x4*>((dst) + 4)  = *reinterpret_cast<const f32x4*>((src) + 4);  \
    *reinterpret_cast<f32x4*>((dst) + 8)  = *reinterpret_cast<const f32x4*>((src) + 8);  \
    *reinterpret_cast<f32x4*>((dst) + 12) = *reinterpret_cast<const f32x4*>((src) + 12); \
    (dst)[16] = (src)[16];

#define PASS(dstp, xw, kv)                                                   \
    {                                                                        \
        float a0 = 0.f, a1 = 0.f, a2 = 0.f, a3 = 0.f;                        \
        _Pragma("unroll")                                                    \
        for (int k = 0; k < 8; ++k) {                                        \
            a0 = fmaf((xw)[0 + k], (kv)[k], a0);                             \
            a1 = fmaf((xw)[3 + k], (kv)[k], a1);                             \
            a2 = fmaf((xw)[6 + k], (kv)[k], a2);                             \
            a3 = fmaf((xw)[9 + k], (kv)[k], a3);                             \
        }                                                                    \
        f32x4 o = {a0, a1, a2, a3};                                          \
        *reinterpret_cast<f32x4*>(dstp) = o;                                 \
    }

__global__ __launch_bounds__(256)
void conv_v7(const float* __restrict__ x, const float* __restrict__ kern,
             float* __restrict__ out) {
    __shared__ float lx[Cn * CSTR];          // 57.7 KB

    const int tid = threadIdx.x;
    const int wq  = blockIdx.x;              // 0..3
    const int b   = blockIdx.y;              // 0..31
    const int gp  = blockIdx.z;              // 0..1

    // ---- stage: dense coalesced reads -> per-channel LDS rows ----
    const int g0 = (wq * (TW * 3) - PADn) * Cn;       // flat float offset
    const float* xb = x + (size_t)b * Sn * Cn;
    for (int i = tid; i < SAMP * Cn; i += 256) {
        int gg = g0 + i;
        float v = (gg >= 0 && gg < Sn * Cn) ? xb[gg] : 0.0f;
        int s = i / 7;
        int c = i - 7 * s;
        lx[c * CSTR + s] = v;
    }
    __syncthreads();

    const int lane = tid & 63;
    const int r    = __builtin_amdgcn_readfirstlane(tid >> 6);   // wave 0..3
    const int n0   = gp ? 36 : 0;
    const int n1   = gp ? 73 : 36;
    const int ch0  = lane, ch1 = lane + 64, ch2 = lane + 128;
    const bool p2  = (ch2 < CHT);            // lanes 0..42

    float* ob = out + (size_t)b * OCH * Wn + 4 * (wq * CHT);

    for (int c = 0; c < Cn; ++c) {
        const float* lc = lx + c * CSTR;
        float xw0[17], xw1[17], xw2[17];
        LOAD17(xw0, lc + 12 * ch0)
        LOAD17(xw1, lc + 12 * ch1)
        if (p2) { LOAD17(xw2, lc + 12 * ch2) }

        for (int n = n0 + r; n < n1; n += 4) {       // wave-uniform rows
            const float* kr = kern + n * Kn;
            float kv[8];
#pragma unroll
            for (int k = 0; k < 8; ++k) kv[k] = kr[k];
            float* orow = ob + (size_t)(n * 7 + c) * Wn;
            PASS(orow + 4 * ch0, xw0, kv)
            PASS(orow + 4 * ch1, xw1, kv)
            if (p2) PASS(orow + 4 * ch2, xw2, kv)
        }
        if (c == 0 && gp == 1 && r == 3) {           // row 511 (kern 73, ch 0)
            const float* kr = kern + 73 * Kn;
            float kv[8];
#pragma unroll
            for (int k = 0; k < 8; ++k) kv[k] = kr[k];
            float* orow = ob + (size_t)511 * Wn;
            PASS(orow + 4 * ch0, xw0, kv)
            PASS(orow + 4 * ch1, xw1, kv)
            if (p2) PASS(orow + 4 * ch2, xw2, kv)
        }
    }
}

extern "C" void kernel_launch(void* const* d_in, const int* in_sizes, int n_in,
                              void* d_out, int out_size, void* d_ws, size_t ws_size,
                              hipStream_t stream) {
    const float* x    = (const float*)d_in[0];
    const float* kern = (const float*)d_in[1];
    float* out        = (float*)d_out;

    conv_v7<<<dim3(4, Bn, 2), 256, 0, stream>>>(x, kern, out);
}